// Round 7
// baseline (404.314 us; speedup 1.0000x reference)
//
#include <hip/hip_runtime.h>
#include <math.h>

// VQ-VAE eval forward via MFMA GEMM.
// inputs: [128,1024,64] fp32, embedding: [512,64] fp32
// out: loss[1] | quantized[8388608] | perplexity[1] | encodings[67108864]
//
// R12: 128 rows/block, 2 row-tiles per wave (R6's verified-correct layout)
// WITHOUT the two poisons that sank R6: no __launch_bounds__ min-waves clamp
// (R6's (256,4) forced VGPR=64 -> scratch spill; ~116 live regs fit under
// 128 -> 4 waves/SIMD), and no threadfence/done-counter (R8's separate
// fence-free vq_final). Mechanism: sweep is latency-bound (per-tile wall
// ~7k cyc vs ~110 issue cyc); halving block count at fixed per-block
// latency and equal residency (4 blocks/CU: LDS 39KB, VGPR<=128) cuts
// sweep time ~38% and halves efrag L2 re-reads.

#define NK 512
#define ND 64
#define NROWS 131072
#define ROWS_PB 128
#define BLOCK 256
#define NBLOCKS (NROWS / ROWS_PB)   // 1024
#define NTILES 32                   // 32 code-tiles of 16
#define XSTRIDE 68                  // lds_x row stride (floats): 16B-aligned, 2-way-bank-free
#define MARGIN 0.02f                // ~150x the hi/lo error bound

#define Q_OFF    1
#define PERP_OFF 8388609
#define ENC_OFF  8388610

typedef float vf2 __attribute__((ext_vector_type(2)));
typedef float vf4 __attribute__((ext_vector_type(4)));
typedef short vs8 __attribute__((ext_vector_type(8)));

__device__ __forceinline__ unsigned short bf16_rne(float v) {
    union { float f; unsigned int u; } a; a.f = v;
    return (unsigned short)((a.u + 0x7FFFu + ((a.u >> 16) & 1u)) >> 16);
}
__device__ __forceinline__ float bf16_to_f(unsigned short s) {
    union { unsigned int u; float f; } a; a.u = ((unsigned int)s) << 16;
    return a.f;
}

// ---- prep: E -> B-fragment stream (hi/lo bf16) + |e|^2 fp32 + ws zeroing ----
// frag f per tile t: f0={eh,k0-31} f1={eh,k32-63} f2={el,k0-31} f3={el,k32-63}
// B-frag lane map (16x16x32): n = lane&15 (code-in-tile), k = (lane>>4)*8 + j
__global__ __launch_bounds__(64) void vq_prep(const float* __restrict__ emb,
                                              float* __restrict__ eknorm,
                                              unsigned int* __restrict__ efrag,
                                              int* __restrict__ ws_zero) {
    const int t = blockIdx.x;        // tile
    const int l = threadIdx.x;       // lane
    if (t == 0) {                    // zero g_counts[512] + g_loss (4 KB)
        #pragma unroll
        for (int i = 0; i < 16; ++i) ws_zero[l + i * 64] = 0;
    }
    const int c = t * 16 + (l & 15);
    const int quad = l >> 4;
    #pragma unroll
    for (int f = 0; f < 4; ++f) {
        const int kbase = (f & 1) * 32 + quad * 8;
        unsigned int w[4];
        #pragma unroll
        for (int d = 0; d < 4; ++d) {
            float v0 = emb[c * ND + kbase + 2 * d];
            float v1 = emb[c * ND + kbase + 2 * d + 1];
            unsigned short h0 = bf16_rne(v0), h1 = bf16_rne(v1);
            unsigned short l0 = bf16_rne(v0 - bf16_to_f(h0));
            unsigned short l1 = bf16_rne(v1 - bf16_to_f(h1));
            unsigned short e0 = (f < 2) ? h0 : l0;
            unsigned short e1 = (f < 2) ? h1 : l1;
            w[d] = (unsigned int)e0 | ((unsigned int)e1 << 16);
        }
        unsigned int* dst = efrag + ((size_t)(t * 4 + f) * 64 + l) * 4;
        dst[0] = w[0]; dst[1] = w[1]; dst[2] = w[2]; dst[3] = w[3];
    }
    if (quad == 0) {   // threads 0..15: eknorm for this tile's 16 codes
        const vf4* er = (const vf4*)(emb + c * ND);
        float s0 = 0.f, s1 = 0.f, s2 = 0.f, s3 = 0.f;
        #pragma unroll
        for (int j = 0; j < 16; ++j) {
            vf4 v = er[j];
            s0 += v.x * v.x; s1 += v.y * v.y; s2 += v.z * v.z; s3 += v.w * v.w;
        }
        eknorm[c] = (s0 + s1) + (s2 + s3);
    }
}

__global__ __launch_bounds__(BLOCK) void vq_main(const float* __restrict__ x,
                                                 const float* __restrict__ emb,
                                                 const float* __restrict__ eknorm,
                                                 const unsigned int* __restrict__ efrag,
                                                 float* __restrict__ out,
                                                 int* __restrict__ g_counts,
                                                 float* __restrict__ g_loss) {
    __shared__ float lds_x[ROWS_PB * XSTRIDE];   // 128 rows x 64 fp32 (stride 68) = 34 KB
    __shared__ float ek_lds[NK];
    __shared__ float d1s[ROWS_PB], d2s[ROWS_PB];
    __shared__ int   i1s[ROWS_PB], i2s[ROWS_PB];
    __shared__ int   idx_s[ROWS_PB];
    __shared__ float red[4];

    const int tid  = threadIdx.x;
    const int wave = tid >> 6;
    const int lane = tid & 63;
    const int col  = lane & 15;
    const int quad = lane >> 4;

    // ---- stage X tile (coalesced float4) + eknorm into LDS ----
    {
        const vf4* xp = (const vf4*)(x + (size_t)blockIdx.x * ROWS_PB * ND);
        #pragma unroll
        for (int i = 0; i < 8; ++i) {
            int e4 = tid + i * BLOCK;          // float4 index 0..2047
            int r  = e4 >> 4;                  // 16 float4 per row
            int c4 = (e4 & 15) * 4;
            *(vf4*)&lds_x[r * XSTRIDE + c4] = xp[e4];
        }
        ek_lds[tid] = eknorm[tid];
        ek_lds[tid + 256] = eknorm[tid + 256];
    }
    __syncthreads();

    // ---- build A-fragments (hi/lo) for TWO row-tiles per wave ----
    // A map: m = lane&15 (row-in-tile), k = quad*8 + j
    const int rowA = wave * 32 + col;
    const int rowB = rowA + 16;
    vs8 ah0a, ah1a, al0a, al1a, ah0b, ah1b, al0b, al1b;
    {
        const float* xr = &lds_x[rowA * XSTRIDE];
        #pragma unroll
        for (int j = 0; j < 8; ++j) {
            float va = xr[quad * 8 + j];
            float vb = xr[32 + quad * 8 + j];
            unsigned short ha = bf16_rne(va);
            unsigned short hb = bf16_rne(vb);
            ah0a[j] = (short)ha; al0a[j] = (short)bf16_rne(va - bf16_to_f(ha));
            ah1a[j] = (short)hb; al1a[j] = (short)bf16_rne(vb - bf16_to_f(hb));
        }
        const float* xs = &lds_x[rowB * XSTRIDE];
        #pragma unroll
        for (int j = 0; j < 8; ++j) {
            float va = xs[quad * 8 + j];
            float vb = xs[32 + quad * 8 + j];
            unsigned short ha = bf16_rne(va);
            unsigned short hb = bf16_rne(vb);
            ah0b[j] = (short)ha; al0b[j] = (short)bf16_rne(va - bf16_to_f(ha));
            ah1b[j] = (short)hb; al1b[j] = (short)bf16_rne(vb - bf16_to_f(hb));
        }
    }

    // ---- sweep 32 code-tiles: 16 MFMA each (2 independent chains), top-2 ----
    float d1[8], d2[8];
    int   i1[8], i2[8];
    #pragma unroll
    for (int s = 0; s < 8; ++s) { d1[s] = INFINITY; d2[s] = INFINITY; i1[s] = 0x7FFFFFFF; i2[s] = 0x7FFFFFFF; }

    const vs8* bbase = (const vs8*)efrag;
    vs8 b0 = bbase[0 * 64 + lane];
    vs8 b1 = bbase[1 * 64 + lane];
    vs8 b2 = bbase[2 * 64 + lane];
    vs8 b3 = bbase[3 * 64 + lane];

    for (int t = 0; t < NTILES; ++t) {
        vs8 n0, n1, n2, n3;
        if (t + 1 < NTILES) {
            n0 = bbase[((t + 1) * 4 + 0) * 64 + lane];
            n1 = bbase[((t + 1) * 4 + 1) * 64 + lane];
            n2 = bbase[((t + 1) * 4 + 2) * 64 + lane];
            n3 = bbase[((t + 1) * 4 + 3) * 64 + lane];
        }
        vf4 accA = {0.f, 0.f, 0.f, 0.f};
        vf4 accB = {0.f, 0.f, 0.f, 0.f};
        accA = __builtin_amdgcn_mfma_f32_16x16x32_bf16(ah0a, b0, accA, 0, 0, 0);
        accB = __builtin_amdgcn_mfma_f32_16x16x32_bf16(ah0b, b0, accB, 0, 0, 0);
        accA = __builtin_amdgcn_mfma_f32_16x16x32_bf16(ah1a, b1, accA, 0, 0, 0);
        accB = __builtin_amdgcn_mfma_f32_16x16x32_bf16(ah1b, b1, accB, 0, 0, 0);
        accA = __builtin_amdgcn_mfma_f32_16x16x32_bf16(al0a, b0, accA, 0, 0, 0);
        accB = __builtin_amdgcn_mfma_f32_16x16x32_bf16(al0b, b0, accB, 0, 0, 0);
        accA = __builtin_amdgcn_mfma_f32_16x16x32_bf16(al1a, b1, accA, 0, 0, 0);
        accB = __builtin_amdgcn_mfma_f32_16x16x32_bf16(al1b, b1, accB, 0, 0, 0);
        accA = __builtin_amdgcn_mfma_f32_16x16x32_bf16(ah0a, b2, accA, 0, 0, 0);
        accB = __builtin_amdgcn_mfma_f32_16x16x32_bf16(ah0b, b2, accB, 0, 0, 0);
        accA = __builtin_amdgcn_mfma_f32_16x16x32_bf16(ah1a, b3, accA, 0, 0, 0);
        accB = __builtin_amdgcn_mfma_f32_16x16x32_bf16(ah1b, b3, accB, 0, 0, 0);
        accA = __builtin_amdgcn_mfma_f32_16x16x32_bf16(al0a, b2, accA, 0, 0, 0);
        accB = __builtin_amdgcn_mfma_f32_16x16x32_bf16(al0b, b2, accB, 0, 0, 0);
        accA = __builtin_amdgcn_mfma_f32_16x16x32_bf16(al1a, b3, accA, 0, 0, 0);
        accB = __builtin_amdgcn_mfma_f32_16x16x32_bf16(al1b, b3, accB, 0, 0, 0);

        const float ek = ek_lds[t * 16 + col];
        const int cidx = t * 16 + col;
        #pragma unroll
        for (int r = 0; r < 4; ++r) {
            {
                float d = ek - 2.f * accA[r];
                bool lt1 = d < d1[r];
                bool lt2 = d < d2[r];
                d2[r] = lt1 ? d1[r] : (lt2 ? d : d2[r]);
                i2[r] = lt1 ? i1[r] : (lt2 ? cidx : i2[r]);
                d1[r] = lt1 ? d : d1[r];
                i1[r] = lt1 ? cidx : i1[r];
            }
            {
                const int s = r + 4;
                float d = ek - 2.f * accB[r];
                bool lt1 = d < d1[s];
                bool lt2 = d < d2[s];
                d2[s] = lt1 ? d1[s] : (lt2 ? d : d2[s]);
                i2[s] = lt1 ? i1[s] : (lt2 ? cidx : i2[s]);
                d1[s] = lt1 ? d : d1[s];
                i1[s] = lt1 ? cidx : i1[s];
            }
        }
        b0 = n0; b1 = n1; b2 = n2; b3 = n3;
    }

    // ---- butterfly-merge top-2 across the 16 lanes holding each row ----
    #pragma unroll
    for (int m = 8; m >= 1; m >>= 1) {
        #pragma unroll
        for (int s = 0; s < 8; ++s) {
            float od1 = __shfl_xor(d1[s], m);
            int   oi1 = __shfl_xor(i1[s], m);
            float od2 = __shfl_xor(d2[s], m);
            int   oi2 = __shfl_xor(i2[s], m);
            bool aF = (d1[s] < od1) || (d1[s] == od1 && i1[s] < oi1);
            float n1 = aF ? d1[s] : od1;  int ni1 = aF ? i1[s] : oi1;
            float ca = aF ? od1 : d1[s];  int cia = aF ? oi1 : i1[s];
            float cb = aF ? d2[s] : od2;  int cib = aF ? i2[s] : oi2;
            bool bF = (cb < ca) || (cb == ca && cib < cia);
            float n2 = bF ? cb : ca;      int ni2 = bF ? cib : cia;
            d1[s] = n1; i1[s] = ni1; d2[s] = n2; i2[s] = ni2;
        }
    }
    if (col == 0) {
        #pragma unroll
        for (int s = 0; s < 8; ++s) {
            // C layout: row = quad*4 + reg; slot s>=4 is the +16 row-tile
            int lr = wave * 32 + (s >> 2) * 16 + quad * 4 + (s & 3);
            d1s[lr] = d1[s]; i1s[lr] = i1[s];
            d2s[lr] = d2[s]; i2s[lr] = i2[s];
        }
    }
    __syncthreads();

    // ---- rescore near-ties in exact fp32; commit argmin + histogram ----
    if (tid < ROWS_PB) {
        int am = i1s[tid];
        if (d2s[tid] - d1s[tid] < MARGIN) {
            int ia = i1s[tid], ib = i2s[tid];
            const float* xr = &lds_x[tid * XSTRIDE];
            float da, db;
            {
                const vf4* er = (const vf4*)(emb + ia * ND);
                float s0 = 0.f, s1 = 0.f, s2 = 0.f, s3 = 0.f;
                #pragma unroll
                for (int j = 0; j < 16; ++j) {
                    vf4 v = er[j];
                    s0 += xr[4 * j] * v.x; s1 += xr[4 * j + 1] * v.y;
                    s2 += xr[4 * j + 2] * v.z; s3 += xr[4 * j + 3] * v.w;
                }
                da = ek_lds[ia] - 2.f * ((s0 + s1) + (s2 + s3));
            }
            {
                const vf4* er = (const vf4*)(emb + ib * ND);
                float s0 = 0.f, s1 = 0.f, s2 = 0.f, s3 = 0.f;
                #pragma unroll
                for (int j = 0; j < 16; ++j) {
                    vf4 v = er[j];
                    s0 += xr[4 * j] * v.x; s1 += xr[4 * j + 1] * v.y;
                    s2 += xr[4 * j + 2] * v.z; s3 += xr[4 * j + 3] * v.w;
                }
                db = ek_lds[ib] - 2.f * ((s0 + s1) + (s2 + s3));
            }
            // numpy first-index semantics on exact distances
            am = ((db < da) || (db == da && ib < ia)) ? ib : ia;
        }
        idx_s[tid] = am;
        atomicAdd(&g_counts[am], 1);
    }
    __syncthreads();

    // ---- quantized gather + exact elementwise loss ----
    float lacc = 0.f;
    {
        float* qout = out + Q_OFF + (size_t)blockIdx.x * ROWS_PB * ND;
        #pragma unroll 4
        for (int i = 0; i < 32; ++i) {
            int p = tid + i * BLOCK;
            int r = p >> 6;
            int c = p & 63;
            float q = emb[idx_s[r] * ND + c];     // wave-uniform row, coalesced
            float xv = lds_x[r * XSTRIDE + c];
            qout[p] = q;
            float dlt = q - xv;
            lacc += dlt * dlt;
        }
    }
    #pragma unroll
    for (int off = 32; off >= 1; off >>= 1) lacc += __shfl_down(lacc, off);
    if (lane == 0) red[wave] = lacc;
    __syncthreads();
    if (tid == 0) atomicAdd(g_loss, (red[0] + red[1]) + (red[2] + red[3]));

    // ---- encodings: one-hot rows, vf2 stores (base is 8B-aligned) ----
    {
        vf2* eout = (vf2*)(out + ENC_OFF) + (size_t)blockIdx.x * ROWS_PB * NK / 2;
        #pragma unroll 4
        for (int i = 0; i < 128; ++i) {
            int p = tid + i * BLOCK;
            int r = p >> 8;          // 256 vf2 per row
            int c2 = p & 255;
            int am = idx_s[r];
            vf2 v = {0.f, 0.f};
            if ((am >> 1) == c2) {
                if (am & 1) v.y = 1.f; else v.x = 1.f;
            }
            eout[p] = v;
        }
    }
}

__global__ __launch_bounds__(512) void vq_final(const int* __restrict__ g_counts,
                                                const float* __restrict__ g_loss,
                                                float* __restrict__ out) {
    __shared__ float red[8];
    int t = threadIdx.x;
    float p = (float)g_counts[t] * (1.0f / (float)NROWS);
    float h = p * logf(p + 1e-10f);
    #pragma unroll
    for (int off = 32; off >= 1; off >>= 1) h += __shfl_down(h, off);
    if ((t & 63) == 0) red[t >> 6] = h;
    __syncthreads();
    if (t == 0) {
        float s = 0.f;
        #pragma unroll
        for (int i = 0; i < 8; ++i) s += red[i];
        out[PERP_OFF] = expf(-s);
        out[0] = 0.25f * g_loss[0] / (float)(NROWS * ND);
    }
}

extern "C" void kernel_launch(void* const* d_in, const int* in_sizes, int n_in,
                              void* d_out, int out_size, void* d_ws, size_t ws_size,
                              hipStream_t stream) {
    const float* x   = (const float*)d_in[0];
    const float* emb = (const float*)d_in[1];
    float* out = (float*)d_out;

    int*          g_counts = (int*)d_ws;                         // 512 ints
    float*        g_loss   = (float*)((char*)d_ws + 2048);       // 1 float
    float*        eknorm   = (float*)((char*)d_ws + 4096);       // 512 floats
    unsigned int* efrag    = (unsigned int*)((char*)d_ws + 8192);// 128 KB frag stream

    // ws re-poisoned to 0xAA before every launch — vq_prep block 0 zeros
    // counts/loss (first 4 KB); eknorm/efrag fully overwritten each call.
    vq_prep<<<NTILES, 64, 0, stream>>>(emb, eknorm, efrag, (int*)d_ws);
    vq_main<<<NBLOCKS, BLOCK, 0, stream>>>(x, emb, eknorm, efrag, out, g_counts, g_loss);
    vq_final<<<1, 512, 0, stream>>>(g_counts, g_loss, out);
}